// Round 13
// baseline (391.353 us; speedup 1.0000x reference)
//
#include <hip/hip_runtime.h>
#include <cmath>

#define B_   64
#define LX_  1024
#define LY_  1024
#define D_   300
#define DP   320      // padded K / e dimension
#define DV   304      // padded d for PV (19 * 16)
#define BM   64       // s-tile rows per block (flash attn)
#define KV   32       // t-tile
#define NT   (LY_ / KV)

using f32x4  = __attribute__((ext_vector_type(4))) float;
using bf16x8 = __attribute__((ext_vector_type(8))) __bf16;
using u32x4  = __attribute__((ext_vector_type(4))) unsigned int;
using u32x2  = __attribute__((ext_vector_type(2))) unsigned int;

static __device__ __forceinline__ unsigned short f2b(float f){
    unsigned u = __builtin_bit_cast(unsigned, f);
    u += 0x7FFFu + ((u >> 16) & 1u);          // round-to-nearest-even
    return (unsigned short)(u >> 16);
}

static __device__ __forceinline__ unsigned pk_bf16(float lo, float hi){
    unsigned r;
    asm volatile("v_cvt_pk_bf16_f32 %0, %1, %2" : "=v"(r) : "v"(lo), "v"(hi));
    return r;
}

static __device__ __forceinline__ bf16x8 ld_bf8(const unsigned short* p){
    u32x4 u = *(const u32x4*)p;
    return __builtin_bit_cast(bf16x8, u);
}

static __device__ __forceinline__ f32x4 mfma16(bf16x8 a, bf16x8 b, f32x4 c){
    return __builtin_amdgcn_mfma_f32_16x16x32_bf16(a, b, c, 0, 0, 0);
}

// ---------------- K0+K2 fused: wconv (blocks >= 5120) + ytrans (blocks < 5120)
__global__ __launch_bounds__(256) void k_pre(const float* __restrict__ Y,
        const int* __restrict__ mask, const float* __restrict__ W,
        unsigned short* __restrict__ yT, unsigned short* __restrict__ Wb){
    const int bid = blockIdx.x;
    const int tid = threadIdx.x;

    if (bid >= 5120){                      // ---- wconv part (400 blocks) ----
        const int i = (bid - 5120) * 256 + tid;
        if (i < DP * DP){
            const int e = i / DP, d = i % DP;
            float v = (e < D_ && d < D_) ? W[e * D_ + d] : 0.f;
            Wb[i] = f2b(v);
        }
        return;
    }

    // ---- ytrans part (5120 blocks): y (b,t,d f32) -> yT (b,d,t bf16) ----
    __shared__ float tile[64][65];
    const int b  = bid / 80;
    const int tt = (bid % 80) / 5;
    const int dt = bid % 5;
    const int t0 = tt * 64, d0 = dt * 64;
    const int dl = tid & 63, qq = tid >> 6;

    // block-uniform skip: all 64 t-rows masked -> yT never consumed
    const int mv = mask[b * LY_ + t0 + dl];
    if (__all(mv != 0)) return;

    #pragma unroll
    for (int r = 0; r < 16; ++r){
        const int tl = qq * 16 + r;
        const int d = d0 + dl;
        float v = (d < D_) ? Y[((long)b * LY_ + t0 + tl) * D_ + d] : 0.f;
        tile[tl][dl] = v;
    }
    __syncthreads();
    #pragma unroll
    for (int r = 0; r < 16; ++r){
        const int drow = d0 + qq * 16 + r;
        if (drow < DV){
            float v = (drow < D_) ? tile[dl][qq * 16 + r] : 0.f;
            yT[((long)b * DV + drow) * LY_ + t0 + dl] = f2b(v);
        }
    }
}

// ---------------- K1: proj = relu(Z @ W^T + b) -------------------------------
// Register diet: two ms-passes, a[10] (40 VGPR) instead of a[2][10] (80).
// Wb re-read per pass is L1-served (10KB/es slice, shared by all 4 waves).
__global__ __launch_bounds__(256, 2) void k_proj(const float* __restrict__ X,
        const float* __restrict__ Y, const float* __restrict__ bias,
        const int* __restrict__ mask, const unsigned short* __restrict__ Wb,
        unsigned short* __restrict__ Px, unsigned short* __restrict__ Py){
    const int tid = threadIdx.x;
    const int w = tid >> 6, l = tid & 63;
    const int lr = l & 15, lg = l >> 4;
    const long m0 = (long)blockIdx.x * 128;
    const bool isX = (m0 < (long)B_ * LX_);
    const float* S = isX ? X : Y;
    unsigned short* Dst = isX ? Px : Py;
    const long base = isX ? m0 : m0 - (long)B_ * LX_;

    if (!isX){
        // per-wave skip: all 32 rows of this wave's y-tile masked
        const int bb = (int)(base >> 10);
        const int trow = ((int)base & 1023) + 32 * w + (l & 31);
        const int mv = mask[bb * LY_ + trow];
        if (__all(mv != 0)) return;
    }

    #pragma unroll 1
    for (int ms = 0; ms < 2; ++ms){
        u32x4 a[10];
        const float* rp = S + (base + 32 * w + 16 * ms + lr) * D_;
        #pragma unroll
        for (int ks = 0; ks < 10; ++ks){
            const int k0 = ks * 32 + lg * 8;
            f32x4 v0 = {0,0,0,0}, v1 = {0,0,0,0};
            if (k0 + 4 <= D_) v0 = *(const f32x4*)(rp + k0);
            if (k0 + 8 <= D_) v1 = *(const f32x4*)(rp + k0 + 4);
            u32x4 u;
            u[0] = pk_bf16(v0[0], v0[1]);
            u[1] = pk_bf16(v0[2], v0[3]);
            u[2] = pk_bf16(v1[0], v1[1]);
            u[3] = pk_bf16(v1[2], v1[3]);
            a[ks] = u;
        }

        #pragma unroll 2
        for (int es = 0; es < 20; ++es){
            f32x4 acc = {0,0,0,0};
            const unsigned short* wp = Wb + (es * 16 + lr) * DP + lg * 8;
            #pragma unroll
            for (int ks = 0; ks < 10; ++ks){
                bf16x8 bf = ld_bf8(wp + ks * 32);       // A: row=e, k=d
                acc = mfma16(bf, __builtin_bit_cast(bf16x8, a[ks]), acc);
            }
            // lane holds D[e = es*16 + 4*lg + r][m = base+32w+16ms+lr]
            const int e0 = es * 16 + lg * 4;
            f32x4 bv = {0,0,0,0};
            if (e0 + 4 <= D_) bv = *(const f32x4*)(bias + e0);
            else {
                #pragma unroll
                for (int r = 0; r < 4; ++r) bv[r] = (e0 + r < D_) ? bias[e0 + r] : 0.f;
            }
            float s0[4];
            #pragma unroll
            for (int r = 0; r < 4; ++r){
                float t0v = acc[r] + bv[r]; s0[r] = t0v > 0.f ? t0v : 0.f;
            }
            const u32x2 o0 = { pk_bf16(s0[0], s0[1]), pk_bf16(s0[2], s0[3]) };
            *(u32x2*)(Dst + (base + 32 * w + 16 * ms + lr) * DP + e0) = o0;
        }
    }
}

// ---------------- K3: flash attention (FROZEN from r12: 303us/166us config) --
// mask is int32: 0 = keep, nonzero = masked out
__global__ __launch_bounds__(256, 2) void k_attn(const int* __restrict__ mask,
        const unsigned short* __restrict__ Px, const unsigned short* __restrict__ Py,
        const unsigned short* __restrict__ yT, float* __restrict__ out){
    __shared__ unsigned short Yp_lds[KV][320];   // linear; XOR-swizzled write/read
    __shared__ unsigned short yT_lds[DV][32];    // linear; XOR-swizzled write/read
    __shared__ unsigned short P_lds[BM][40];     // padded (ds-written)

    const int tid = threadIdx.x;
    const int w = tid >> 6, l = tid & 63;
    const int lr = l & 15, lg = l >> 4;
    const int sw3 = lr & 7;          // Yp read swizzle: chunk ^= sw3
    const int s2  = (lr >> 1) & 3;   // yT read swizzle: chunk ^= s2

    // XCD-bijective swizzle: all 16 s-blocks of a batch land on one XCD
    const int bid = blockIdx.x;              // 1024
    const int xcd = bid & 7;
    const int g = bid >> 3;
    const int b = xcd + 8 * (g >> 4);
    const int s0 = (g & 15) * BM;

    // Q fragments: wave w owns rows s0+16w .. s0+16w+15 (B-operand: col = lr)
    u32x4 q[10];
    {
        const unsigned short* qp = Px + ((long)b * LX_ + s0 + 16 * w + lr) * DP + lg * 8;
        #pragma unroll
        for (int ks = 0; ks < 10; ++ks) q[ks] = *(const u32x4*)(qp + ks * 32);
    }

    // ---- staging address setup (loop-invariant; dst chunk XOR-swizzled) ----
    const unsigned short* srcYp[5];
    unsigned short*       dstYp[5];
    #pragma unroll
    for (int j = 0; j < 5; ++j){
        const int id = tid + 256 * j;            // 0..1279
        const int row = id / 40, c = id % 40;
        srcYp[j] = Py + ((long)b * LY_ + row) * DP + c * 8;
        dstYp[j] = &Yp_lds[row][(c ^ (row & 7)) * 8];
    }
    const unsigned short* srcYT[5];
    unsigned short*       dstYT[5];
    #pragma unroll
    for (int j = 0; j < 5; ++j){
        const int id = tid + 256 * j;            // valid if < 1216
        const int row = (id >> 2) < DV ? (id >> 2) : (DV - 1);
        const int c = id & 3;
        srcYT[j] = yT + ((long)b * DV + row) * LY_ + c * 8;
        dstYT[j] = &yT_lds[row][(c ^ ((row >> 1) & 3)) * 8];
    }
    const bool v4 = (tid < 192);                 // j=4 validity for yT chunks

    const int* mrow = mask + (long)b * LY_;

    // ---- prologue: stage tile 0 ----
    u32x4 pA[5], pT[5];
    #pragma unroll
    for (int j = 0; j < 5; ++j) pA[j] = *(const u32x4*)srcYp[j];
    #pragma unroll
    for (int j = 0; j < 4; ++j) pT[j] = *(const u32x4*)srcYT[j];
    if (v4) pT[4] = *(const u32x4*)srcYT[4];
    int4 m0v = *(const int4*)(mrow + lg * 4);
    int4 m1v = *(const int4*)(mrow + 16 + lg * 4);
    #pragma unroll
    for (int j = 0; j < 5; ++j) *(u32x4*)dstYp[j] = pA[j];
    #pragma unroll
    for (int j = 0; j < 4; ++j) *(u32x4*)dstYT[j] = pT[j];
    if (v4) *(u32x4*)dstYT[4] = pT[4];
    __syncthreads();

    f32x4 acc[19];
    #pragma unroll
    for (int n = 0; n < 19; ++n) acc[n] = f32x4{0,0,0,0};
    float m_r = -INFINITY;    // running max for s-row = s0+16w+lr
    float l_r = 0.f;

    for (int it = 0; it < NT; ++it){
        const bool notlast = (it < NT - 1);

        // ---- A: issue next tile's global loads (consumed after barrier) ----
        int4 mn0, mn1;
        if (notlast){
            #pragma unroll
            for (int j = 0; j < 5; ++j){ srcYp[j] += KV * DP; pA[j] = *(const u32x4*)srcYp[j]; }
            #pragma unroll
            for (int j = 0; j < 4; ++j){ srcYT[j] += KV;      pT[j] = *(const u32x4*)srcYT[j]; }
            srcYT[4] += KV;
            if (v4) pT[4] = *(const u32x4*)srcYT[4];
            mn0 = *(const int4*)(mrow + (it + 1) * KV + lg * 4);
            mn1 = *(const int4*)(mrow + (it + 1) * KV + 16 + lg * 4);
        }

        // ---- B: compute on current tile (skip if fully masked) ----
        const int allm = (m0v.x && m0v.y && m0v.z && m0v.w &&
                          m1v.x && m1v.y && m1v.z && m1v.w) ? 1 : 0;
        if (!__all(allm)){
            // S^T = Yp @ Q^T : lane holds S[t = it*KV+16*sub+4*lg+r][s = s0+16w+lr]
            f32x4 sv0 = {0,0,0,0}, sv1 = {0,0,0,0};
            #pragma unroll
            for (int ks = 0; ks < 10; ++ks){
                const int cc = (((ks << 2) | lg) ^ sw3) << 3;   // swizzled u16 col
                bf16x8 qf = __builtin_bit_cast(bf16x8, q[ks]);
                bf16x8 a0 = ld_bf8(&Yp_lds[lr][cc]);
                bf16x8 a1 = ld_bf8(&Yp_lds[16 + lr][cc]);
                sv0 = mfma16(a0, qf, sv0);
                sv1 = mfma16(a1, qf, sv1);
            }

            float v0[4], v1[4];
            v0[0] = sv0[0] + (m0v.x ? -3.0e38f : 0.f);
            v0[1] = sv0[1] + (m0v.y ? -3.0e38f : 0.f);
            v0[2] = sv0[2] + (m0v.z ? -3.0e38f : 0.f);
            v0[3] = sv0[3] + (m0v.w ? -3.0e38f : 0.f);
            v1[0] = sv1[0] + (m1v.x ? -3.0e38f : 0.f);
            v1[1] = sv1[1] + (m1v.y ? -3.0e38f : 0.f);
            v1[2] = sv1[2] + (m1v.z ? -3.0e38f : 0.f);
            v1[3] = sv1[3] + (m1v.w ? -3.0e38f : 0.f);

            float mx = fmaxf(fmaxf(fmaxf(v0[0], v0[1]), fmaxf(v0[2], v0[3])),
                             fmaxf(fmaxf(v1[0], v1[1]), fmaxf(v1[2], v1[3])));
            mx = fmaxf(mx, __shfl_xor(mx, 16));
            mx = fmaxf(mx, __shfl_xor(mx, 32));
            const float nm = fmaxf(m_r, mx);

            float p0[4], p1[4];
            float ps = 0.f;
            #pragma unroll
            for (int r = 0; r < 4; ++r){
                p0[r] = __expf(v0[r] - nm);
                p1[r] = __expf(v1[r] - nm);
                ps += p0[r] + p1[r];
            }
            ps += __shfl_xor(ps, 16);
            ps += __shfl_xor(ps, 32);
            const float sc = __expf(m_r - nm);   // first tile: exp(-inf)=0
            l_r = l_r * sc + ps;
            m_r = nm;

            // rescale acc rows (s = 4*lg + r): broadcast sc from lane 4*lg+r
            float scr[4];
            #pragma unroll
            for (int r = 0; r < 4; ++r) scr[r] = __shfl(sc, lg * 4 + r);
            #pragma unroll
            for (int n = 0; n < 19; ++n){
                #pragma unroll
                for (int r = 0; r < 4; ++r) acc[n][r] *= scr[r];
            }

            // pack P -> bf16, write own wave's rows (within-wave dependency only)
            const unsigned c00 = pk_bf16(p0[0], p0[1]);
            const unsigned c01 = pk_bf16(p0[2], p0[3]);
            const unsigned c10 = pk_bf16(p1[0], p1[1]);
            const unsigned c11 = pk_bf16(p1[2], p1[3]);
            *(u32x2*)&P_lds[16 * w + lr][4 * lg]      = u32x2{c00, c01};
            *(u32x2*)&P_lds[16 * w + lr][16 + 4 * lg] = u32x2{c10, c11};

            // O += P @ y (yT read with swizzled chunk)
            bf16x8 pf = ld_bf8(&P_lds[16 * w + lr][lg * 8]);
            const int vcc = (lg ^ s2) << 3;
            #pragma unroll
            for (int n = 0; n < 19; ++n){
                bf16x8 vf = ld_bf8(&yT_lds[n * 16 + lr][vcc]);
                acc[n] = mfma16(pf, vf, acc[n]);
            }
        }

        __syncthreads();           // all waves done reading LDS
        if (notlast){
            #pragma unroll
            for (int j = 0; j < 5; ++j) *(u32x4*)dstYp[j] = pA[j];
            #pragma unroll
            for (int j = 0; j < 4; ++j) *(u32x4*)dstYT[j] = pT[j];
            if (v4) *(u32x4*)dstYT[4] = pT[4];
            m0v = mn0; m1v = mn1;
        }
        __syncthreads();           // LDS ready for next iteration
    }

    // normalize: 1/l for rows s = 4*lg + r via broadcast
    const float il = 1.f / l_r;
    float invr[4];
    #pragma unroll
    for (int r = 0; r < 4; ++r) invr[r] = __shfl(il, lg * 4 + r);

    #pragma unroll
    for (int n = 0; n < 19; ++n){
        const int d = n * 16 + lr;
        if (d < D_){
            #pragma unroll
            for (int r = 0; r < 4; ++r){
                out[((long)b * LX_ + s0 + 16 * w + lg * 4 + r) * D_ + d] = acc[n][r] * invr[r];
            }
        }
    }
}

extern "C" void kernel_launch(void* const* d_in, const int* in_sizes, int n_in,
                              void* d_out, int out_size, void* d_ws, size_t ws_size,
                              hipStream_t stream){
    const float* x = (const float*)d_in[0];
    const float* y = (const float*)d_in[1];
    const int* ymask = (const int*)d_in[2];
    const float* W = (const float*)d_in[3];
    const float* bias = (const float*)d_in[4];
    float* out = (float*)d_out;

    unsigned short* Wb  = (unsigned short*)d_ws;
    unsigned short* Px  = (unsigned short*)((char*)d_ws + (1 << 18));
    unsigned short* Py  = (unsigned short*)((char*)d_ws + (1 << 18) + 41943040LL);
    unsigned short* yTw = (unsigned short*)((char*)d_ws + (1 << 18) + 83886080LL);

    // k_pre: 5120 ytrans blocks + 400 wconv blocks (independent outputs)
    hipLaunchKernelGGL(k_pre,  dim3(5520), dim3(256), 0, stream, y, ymask, W, yTw, Wb);
    hipLaunchKernelGGL(k_proj, dim3(1024), dim3(256), 0, stream, x, y, bias, ymask, Wb, Px, Py);
    hipLaunchKernelGGL(k_attn, dim3(1024), dim3(256), 0, stream, ymask, Px, Py, yTw, out);
}

// Round 14
// 301.296 us; speedup vs baseline: 1.2989x; 1.2989x over previous
//
#include <hip/hip_runtime.h>
#include <cmath>

#define B_   64
#define LX_  1024
#define LY_  1024
#define D_   300
#define DP   320      // padded K / e dimension
#define DV   304      // padded d for PV (19 * 16)
#define BM   64       // s-tile rows per block (flash attn)
#define KV   32       // t-tile
#define NT   (LY_ / KV)

using f32x4  = __attribute__((ext_vector_type(4))) float;
using bf16x8 = __attribute__((ext_vector_type(8))) __bf16;
using u32x4  = __attribute__((ext_vector_type(4))) unsigned int;
using u32x2  = __attribute__((ext_vector_type(2))) unsigned int;

static __device__ __forceinline__ unsigned short f2b(float f){
    unsigned u = __builtin_bit_cast(unsigned, f);
    u += 0x7FFFu + ((u >> 16) & 1u);          // round-to-nearest-even
    return (unsigned short)(u >> 16);
}

static __device__ __forceinline__ unsigned pk_bf16(float lo, float hi){
    unsigned r;
    asm volatile("v_cvt_pk_bf16_f32 %0, %1, %2" : "=v"(r) : "v"(lo), "v"(hi));
    return r;
}

static __device__ __forceinline__ bf16x8 ld_bf8(const unsigned short* p){
    u32x4 u = *(const u32x4*)p;
    return __builtin_bit_cast(bf16x8, u);
}

static __device__ __forceinline__ f32x4 mfma16(bf16x8 a, bf16x8 b, f32x4 c){
    return __builtin_amdgcn_mfma_f32_16x16x32_bf16(a, b, c, 0, 0, 0);
}

// ---------------- K0+K2 fused: wconv (blocks >= 5120) + ytrans (blocks < 5120)
__global__ __launch_bounds__(256) void k_pre(const float* __restrict__ Y,
        const int* __restrict__ mask, const float* __restrict__ W,
        unsigned short* __restrict__ yT, unsigned short* __restrict__ Wb){
    const int bid = blockIdx.x;
    const int tid = threadIdx.x;

    if (bid >= 5120){                      // ---- wconv part (400 blocks) ----
        const int i = (bid - 5120) * 256 + tid;
        if (i < DP * DP){
            const int e = i / DP, d = i % DP;
            float v = (e < D_ && d < D_) ? W[e * D_ + d] : 0.f;
            Wb[i] = f2b(v);
        }
        return;
    }

    // ---- ytrans part (5120 blocks): y (b,t,d f32) -> yT (b,d,t bf16) ----
    __shared__ float tile[64][65];
    const int b  = bid / 80;
    const int tt = (bid % 80) / 5;
    const int dt = bid % 5;
    const int t0 = tt * 64, d0 = dt * 64;
    const int dl = tid & 63, qq = tid >> 6;

    // block-uniform skip: all 64 t-rows masked -> yT never consumed
    const int mv = mask[b * LY_ + t0 + dl];
    if (__all(mv != 0)) return;

    #pragma unroll
    for (int r = 0; r < 16; ++r){
        const int tl = qq * 16 + r;
        const int d = d0 + dl;
        float v = (d < D_) ? Y[((long)b * LY_ + t0 + tl) * D_ + d] : 0.f;
        tile[tl][dl] = v;
    }
    __syncthreads();
    #pragma unroll
    for (int r = 0; r < 16; ++r){
        const int drow = d0 + qq * 16 + r;
        if (drow < DV){
            float v = (drow < D_) ? tile[dl][qq * 16 + r] : 0.f;
            yT[((long)b * DV + drow) * LY_ + t0 + dl] = f2b(v);
        }
    }
}

// ---------------- K1: proj = relu(Z @ W^T + b) -------------------------------
// r12 version: TWO independent accumulator chains per wave (a[2][10], 80 VGPR)
// -- this ILP is load-bearing (r13's single-chain diet: MfmaUtil 4%, 2.3x slower).
__global__ __launch_bounds__(256) void k_proj(const float* __restrict__ X,
        const float* __restrict__ Y, const float* __restrict__ bias,
        const int* __restrict__ mask, const unsigned short* __restrict__ Wb,
        unsigned short* __restrict__ Px, unsigned short* __restrict__ Py){
    const int tid = threadIdx.x;
    const int w = tid >> 6, l = tid & 63;
    const int lr = l & 15, lg = l >> 4;
    const long m0 = (long)blockIdx.x * 128;
    const bool isX = (m0 < (long)B_ * LX_);
    const float* S = isX ? X : Y;
    unsigned short* Dst = isX ? Px : Py;
    const long base = isX ? m0 : m0 - (long)B_ * LX_;

    if (!isX){
        // per-wave skip: all 32 rows of this wave's y-tile masked
        const int bb = (int)(base >> 10);
        const int trow = ((int)base & 1023) + 32 * w + (l & 31);
        const int mv = mask[bb * LY_ + trow];
        if (__all(mv != 0)) return;
    }

    u32x4 a[2][10];
    #pragma unroll
    for (int ms = 0; ms < 2; ++ms){
        const float* rp = S + (base + 32 * w + 16 * ms + lr) * D_;
        #pragma unroll
        for (int ks = 0; ks < 10; ++ks){
            const int k0 = ks * 32 + lg * 8;
            f32x4 v0 = {0,0,0,0}, v1 = {0,0,0,0};
            if (k0 + 4 <= D_) v0 = *(const f32x4*)(rp + k0);
            if (k0 + 8 <= D_) v1 = *(const f32x4*)(rp + k0 + 4);
            u32x4 u;
            u[0] = pk_bf16(v0[0], v0[1]);
            u[1] = pk_bf16(v0[2], v0[3]);
            u[2] = pk_bf16(v1[0], v1[1]);
            u[3] = pk_bf16(v1[2], v1[3]);
            a[ms][ks] = u;
        }
    }

    #pragma unroll 2
    for (int es = 0; es < 20; ++es){
        f32x4 acc0 = {0,0,0,0}, acc1 = {0,0,0,0};
        const unsigned short* wp = Wb + (es * 16 + lr) * DP + lg * 8;
        #pragma unroll
        for (int ks = 0; ks < 10; ++ks){
            bf16x8 bf = ld_bf8(wp + ks * 32);       // A: row=e, k=d
            acc0 = mfma16(bf, __builtin_bit_cast(bf16x8, a[0][ks]), acc0);
            acc1 = mfma16(bf, __builtin_bit_cast(bf16x8, a[1][ks]), acc1);
        }
        // lane holds D[e = es*16 + 4*lg + r][m = lr]
        const int e0 = es * 16 + lg * 4;
        f32x4 bv = {0,0,0,0};
        if (e0 + 4 <= D_) bv = *(const f32x4*)(bias + e0);
        else {
            #pragma unroll
            for (int r = 0; r < 4; ++r) bv[r] = (e0 + r < D_) ? bias[e0 + r] : 0.f;
        }
        float s0[4], s1[4];
        #pragma unroll
        for (int r = 0; r < 4; ++r){
            float t0v = acc0[r] + bv[r]; s0[r] = t0v > 0.f ? t0v : 0.f;
            float t1v = acc1[r] + bv[r]; s1[r] = t1v > 0.f ? t1v : 0.f;
        }
        const u32x2 o0 = { pk_bf16(s0[0], s0[1]), pk_bf16(s0[2], s0[3]) };
        const u32x2 o1 = { pk_bf16(s1[0], s1[1]), pk_bf16(s1[2], s1[3]) };
        *(u32x2*)(Dst + (base + 32 * w + lr) * DP + e0)      = o0;
        *(u32x2*)(Dst + (base + 32 * w + 16 + lr) * DP + e0) = o1;
    }
}

// ---------------- K3: flash attention (FROZEN from r12: 303us/166us config) --
// mask is int32: 0 = keep, nonzero = masked out
__global__ __launch_bounds__(256, 2) void k_attn(const int* __restrict__ mask,
        const unsigned short* __restrict__ Px, const unsigned short* __restrict__ Py,
        const unsigned short* __restrict__ yT, float* __restrict__ out){
    __shared__ unsigned short Yp_lds[KV][320];   // linear; XOR-swizzled write/read
    __shared__ unsigned short yT_lds[DV][32];    // linear; XOR-swizzled write/read
    __shared__ unsigned short P_lds[BM][40];     // padded (ds-written)

    const int tid = threadIdx.x;
    const int w = tid >> 6, l = tid & 63;
    const int lr = l & 15, lg = l >> 4;
    const int sw3 = lr & 7;          // Yp read swizzle: chunk ^= sw3
    const int s2  = (lr >> 1) & 3;   // yT read swizzle: chunk ^= s2

    // XCD-bijective swizzle: all 16 s-blocks of a batch land on one XCD
    const int bid = blockIdx.x;              // 1024
    const int xcd = bid & 7;
    const int g = bid >> 3;
    const int b = xcd + 8 * (g >> 4);
    const int s0 = (g & 15) * BM;

    // Q fragments: wave w owns rows s0+16w .. s0+16w+15 (B-operand: col = lr)
    u32x4 q[10];
    {
        const unsigned short* qp = Px + ((long)b * LX_ + s0 + 16 * w + lr) * DP + lg * 8;
        #pragma unroll
        for (int ks = 0; ks < 10; ++ks) q[ks] = *(const u32x4*)(qp + ks * 32);
    }

    // ---- staging address setup (loop-invariant; dst chunk XOR-swizzled) ----
    const unsigned short* srcYp[5];
    unsigned short*       dstYp[5];
    #pragma unroll
    for (int j = 0; j < 5; ++j){
        const int id = tid + 256 * j;            // 0..1279
        const int row = id / 40, c = id % 40;
        srcYp[j] = Py + ((long)b * LY_ + row) * DP + c * 8;
        dstYp[j] = &Yp_lds[row][(c ^ (row & 7)) * 8];
    }
    const unsigned short* srcYT[5];
    unsigned short*       dstYT[5];
    #pragma unroll
    for (int j = 0; j < 5; ++j){
        const int id = tid + 256 * j;            // valid if < 1216
        const int row = (id >> 2) < DV ? (id >> 2) : (DV - 1);
        const int c = id & 3;
        srcYT[j] = yT + ((long)b * DV + row) * LY_ + c * 8;
        dstYT[j] = &yT_lds[row][(c ^ ((row >> 1) & 3)) * 8];
    }
    const bool v4 = (tid < 192);                 // j=4 validity for yT chunks

    const int* mrow = mask + (long)b * LY_;

    // ---- prologue: stage tile 0 ----
    u32x4 pA[5], pT[5];
    #pragma unroll
    for (int j = 0; j < 5; ++j) pA[j] = *(const u32x4*)srcYp[j];
    #pragma unroll
    for (int j = 0; j < 4; ++j) pT[j] = *(const u32x4*)srcYT[j];
    if (v4) pT[4] = *(const u32x4*)srcYT[4];
    int4 m0v = *(const int4*)(mrow + lg * 4);
    int4 m1v = *(const int4*)(mrow + 16 + lg * 4);
    #pragma unroll
    for (int j = 0; j < 5; ++j) *(u32x4*)dstYp[j] = pA[j];
    #pragma unroll
    for (int j = 0; j < 4; ++j) *(u32x4*)dstYT[j] = pT[j];
    if (v4) *(u32x4*)dstYT[4] = pT[4];
    __syncthreads();

    f32x4 acc[19];
    #pragma unroll
    for (int n = 0; n < 19; ++n) acc[n] = f32x4{0,0,0,0};
    float m_r = -INFINITY;    // running max for s-row = s0+16w+lr
    float l_r = 0.f;

    for (int it = 0; it < NT; ++it){
        const bool notlast = (it < NT - 1);

        // ---- A: issue next tile's global loads (consumed after barrier) ----
        int4 mn0, mn1;
        if (notlast){
            #pragma unroll
            for (int j = 0; j < 5; ++j){ srcYp[j] += KV * DP; pA[j] = *(const u32x4*)srcYp[j]; }
            #pragma unroll
            for (int j = 0; j < 4; ++j){ srcYT[j] += KV;      pT[j] = *(const u32x4*)srcYT[j]; }
            srcYT[4] += KV;
            if (v4) pT[4] = *(const u32x4*)srcYT[4];
            mn0 = *(const int4*)(mrow + (it + 1) * KV + lg * 4);
            mn1 = *(const int4*)(mrow + (it + 1) * KV + 16 + lg * 4);
        }

        // ---- B: compute on current tile (skip if fully masked) ----
        const int allm = (m0v.x && m0v.y && m0v.z && m0v.w &&
                          m1v.x && m1v.y && m1v.z && m1v.w) ? 1 : 0;
        if (!__all(allm)){
            // S^T = Yp @ Q^T : lane holds S[t = it*KV+16*sub+4*lg+r][s = s0+16w+lr]
            f32x4 sv0 = {0,0,0,0}, sv1 = {0,0,0,0};
            #pragma unroll
            for (int ks = 0; ks < 10; ++ks){
                const int cc = (((ks << 2) | lg) ^ sw3) << 3;   // swizzled u16 col
                bf16x8 qf = __builtin_bit_cast(bf16x8, q[ks]);
                bf16x8 a0 = ld_bf8(&Yp_lds[lr][cc]);
                bf16x8 a1 = ld_bf8(&Yp_lds[16 + lr][cc]);
                sv0 = mfma16(a0, qf, sv0);
                sv1 = mfma16(a1, qf, sv1);
            }

            float v0[4], v1[4];
            v0[0] = sv0[0] + (m0v.x ? -3.0e38f : 0.f);
            v0[1] = sv0[1] + (m0v.y ? -3.0e38f : 0.f);
            v0[2] = sv0[2] + (m0v.z ? -3.0e38f : 0.f);
            v0[3] = sv0[3] + (m0v.w ? -3.0e38f : 0.f);
            v1[0] = sv1[0] + (m1v.x ? -3.0e38f : 0.f);
            v1[1] = sv1[1] + (m1v.y ? -3.0e38f : 0.f);
            v1[2] = sv1[2] + (m1v.z ? -3.0e38f : 0.f);
            v1[3] = sv1[3] + (m1v.w ? -3.0e38f : 0.f);

            float mx = fmaxf(fmaxf(fmaxf(v0[0], v0[1]), fmaxf(v0[2], v0[3])),
                             fmaxf(fmaxf(v1[0], v1[1]), fmaxf(v1[2], v1[3])));
            mx = fmaxf(mx, __shfl_xor(mx, 16));
            mx = fmaxf(mx, __shfl_xor(mx, 32));
            const float nm = fmaxf(m_r, mx);

            float p0[4], p1[4];
            float ps = 0.f;
            #pragma unroll
            for (int r = 0; r < 4; ++r){
                p0[r] = __expf(v0[r] - nm);
                p1[r] = __expf(v1[r] - nm);
                ps += p0[r] + p1[r];
            }
            ps += __shfl_xor(ps, 16);
            ps += __shfl_xor(ps, 32);
            const float sc = __expf(m_r - nm);   // first tile: exp(-inf)=0
            l_r = l_r * sc + ps;
            m_r = nm;

            // rescale acc rows (s = 4*lg + r): broadcast sc from lane 4*lg+r
            float scr[4];
            #pragma unroll
            for (int r = 0; r < 4; ++r) scr[r] = __shfl(sc, lg * 4 + r);
            #pragma unroll
            for (int n = 0; n < 19; ++n){
                #pragma unroll
                for (int r = 0; r < 4; ++r) acc[n][r] *= scr[r];
            }

            // pack P -> bf16, write own wave's rows (within-wave dependency only)
            const unsigned c00 = pk_bf16(p0[0], p0[1]);
            const unsigned c01 = pk_bf16(p0[2], p0[3]);
            const unsigned c10 = pk_bf16(p1[0], p1[1]);
            const unsigned c11 = pk_bf16(p1[2], p1[3]);
            *(u32x2*)&P_lds[16 * w + lr][4 * lg]      = u32x2{c00, c01};
            *(u32x2*)&P_lds[16 * w + lr][16 + 4 * lg] = u32x2{c10, c11};

            // O += P @ y (yT read with swizzled chunk)
            bf16x8 pf = ld_bf8(&P_lds[16 * w + lr][lg * 8]);
            const int vcc = (lg ^ s2) << 3;
            #pragma unroll
            for (int n = 0; n < 19; ++n){
                bf16x8 vf = ld_bf8(&yT_lds[n * 16 + lr][vcc]);
                acc[n] = mfma16(pf, vf, acc[n]);
            }
        }

        __syncthreads();           // all waves done reading LDS
        if (notlast){
            #pragma unroll
            for (int j = 0; j < 5; ++j) *(u32x4*)dstYp[j] = pA[j];
            #pragma unroll
            for (int j = 0; j < 4; ++j) *(u32x4*)dstYT[j] = pT[j];
            if (v4) *(u32x4*)dstYT[4] = pT[4];
            m0v = mn0; m1v = mn1;
        }
        __syncthreads();           // LDS ready for next iteration
    }

    // normalize: 1/l for rows s = 4*lg + r via broadcast
    const float il = 1.f / l_r;
    float invr[4];
    #pragma unroll
    for (int r = 0; r < 4; ++r) invr[r] = __shfl(il, lg * 4 + r);

    #pragma unroll
    for (int n = 0; n < 19; ++n){
        const int d = n * 16 + lr;
        if (d < D_){
            #pragma unroll
            for (int r = 0; r < 4; ++r){
                out[((long)b * LX_ + s0 + 16 * w + lg * 4 + r) * D_ + d] = acc[n][r] * invr[r];
            }
        }
    }
}

extern "C" void kernel_launch(void* const* d_in, const int* in_sizes, int n_in,
                              void* d_out, int out_size, void* d_ws, size_t ws_size,
                              hipStream_t stream){
    const float* x = (const float*)d_in[0];
    const float* y = (const float*)d_in[1];
    const int* ymask = (const int*)d_in[2];
    const float* W = (const float*)d_in[3];
    const float* bias = (const float*)d_in[4];
    float* out = (float*)d_out;

    unsigned short* Wb  = (unsigned short*)d_ws;
    unsigned short* Px  = (unsigned short*)((char*)d_ws + (1 << 18));
    unsigned short* Py  = (unsigned short*)((char*)d_ws + (1 << 18) + 41943040LL);
    unsigned short* yTw = (unsigned short*)((char*)d_ws + (1 << 18) + 83886080LL);

    // k_pre: 5120 ytrans blocks + 400 wconv blocks (independent outputs)
    hipLaunchKernelGGL(k_pre,  dim3(5520), dim3(256), 0, stream, y, ymask, W, yTw, Wb);
    hipLaunchKernelGGL(k_proj, dim3(1024), dim3(256), 0, stream, x, y, bias, ymask, Wb, Px, Py);
    hipLaunchKernelGGL(k_attn, dim3(1024), dim3(256), 0, stream, ymask, Px, Py, yTw, out);
}

// Round 15
// 248.731 us; speedup vs baseline: 1.5734x; 1.2113x over previous
//
#include <hip/hip_runtime.h>
#include <cmath>

#define B_   64
#define LX_  1024
#define LY_  1024
#define D_   300
#define DP   320      // padded K / e dimension
#define DV   304      // padded d for PV (19 * 16)
#define BM   64       // s-tile rows per block (flash attn)
#define KV   32       // t-tile
#define NT   (LY_ / KV)

using f32x4  = __attribute__((ext_vector_type(4))) float;
using bf16x8 = __attribute__((ext_vector_type(8))) __bf16;
using u32x4  = __attribute__((ext_vector_type(4))) unsigned int;
using u32x2  = __attribute__((ext_vector_type(2))) unsigned int;

static __device__ __forceinline__ unsigned short f2b(float f){
    unsigned u = __builtin_bit_cast(unsigned, f);
    u += 0x7FFFu + ((u >> 16) & 1u);          // round-to-nearest-even
    return (unsigned short)(u >> 16);
}

static __device__ __forceinline__ unsigned pk_bf16(float lo, float hi){
    unsigned r;
    asm volatile("v_cvt_pk_bf16_f32 %0, %1, %2" : "=v"(r) : "v"(lo), "v"(hi));
    return r;
}

static __device__ __forceinline__ bf16x8 ld_bf8(const unsigned short* p){
    u32x4 u = *(const u32x4*)p;
    return __builtin_bit_cast(bf16x8, u);
}

static __device__ __forceinline__ f32x4 mfma16(bf16x8 a, bf16x8 b, f32x4 c){
    return __builtin_amdgcn_mfma_f32_16x16x32_bf16(a, b, c, 0, 0, 0);
}

// ---------------- K0+K2 fused: wconv (blocks >= 5120) + ytrans (blocks < 5120)
__global__ __launch_bounds__(256) void k_pre(const float* __restrict__ Y,
        const int* __restrict__ mask, const float* __restrict__ W,
        unsigned short* __restrict__ yT, unsigned short* __restrict__ Wb){
    const int bid = blockIdx.x;
    const int tid = threadIdx.x;

    if (bid >= 5120){                      // ---- wconv part (400 blocks) ----
        const int i = (bid - 5120) * 256 + tid;
        if (i < DP * DP){
            const int e = i / DP, d = i % DP;
            float v = (e < D_ && d < D_) ? W[e * D_ + d] : 0.f;
            Wb[i] = f2b(v);
        }
        return;
    }

    // ---- ytrans part (5120 blocks): y (b,t,d f32) -> yT (b,d,t bf16) ----
    __shared__ float tile[64][65];
    const int b  = bid / 80;
    const int tt = (bid % 80) / 5;
    const int dt = bid % 5;
    const int t0 = tt * 64, d0 = dt * 64;
    const int dl = tid & 63, qq = tid >> 6;

    // block-uniform skip: all 64 t-rows masked -> yT never consumed
    const int mv = mask[b * LY_ + t0 + dl];
    if (__all(mv != 0)) return;

    #pragma unroll
    for (int r = 0; r < 16; ++r){
        const int tl = qq * 16 + r;
        const int d = d0 + dl;
        float v = (d < D_) ? Y[((long)b * LY_ + t0 + tl) * D_ + d] : 0.f;
        tile[tl][dl] = v;
    }
    __syncthreads();
    #pragma unroll
    for (int r = 0; r < 16; ++r){
        const int drow = d0 + qq * 16 + r;
        if (drow < DV){
            float v = (drow < D_) ? tile[dl][qq * 16 + r] : 0.f;
            yT[((long)b * DV + drow) * LY_ + t0 + dl] = f2b(v);
        }
    }
}

// ---------------- K1: proj = relu(Z @ W^T + b) -------------------------------
// Dual-chain MFMA (load-bearing, r13 lesson) + Wb slices staged through LDS:
// all 4 waves broadcast-read the same fragment instead of 4x redundant L2
// loads; slice prefetch (regs) overlaps compute, k_attn's proven pattern.
__global__ __launch_bounds__(256) void k_proj(const float* __restrict__ X,
        const float* __restrict__ Y, const float* __restrict__ bias,
        const int* __restrict__ mask, const unsigned short* __restrict__ Wb,
        unsigned short* __restrict__ Px, unsigned short* __restrict__ Py){
    __shared__ unsigned short Wl[2][32][320];    // 2 x 20KB, XOR-swizzled chunks
    __shared__ int s_skip;

    const int tid = threadIdx.x;
    const int w = tid >> 6, l = tid & 63;
    const int lr = l & 15, lg = l >> 4;
    const int sw3 = lr & 7;
    const long m0 = (long)blockIdx.x * 128;
    const bool isX = (m0 < (long)B_ * LX_);
    const float* S = isX ? X : Y;
    unsigned short* Dst = isX ? Px : Py;
    const long base = isX ? m0 : m0 - (long)B_ * LX_;

    // block-uniform masked skip (barrier-safe: decided before any staging)
    int unmask = 1;
    if (!isX){
        const int bb = (int)(base >> 10);
        const int trow = ((int)base & 1023) + (tid & 127);
        unmask = (mask[bb * LY_ + trow] == 0) ? 1 : 0;
    }
    if (tid == 0) s_skip = 1;
    __syncthreads();
    if (unmask) s_skip = 0;
    __syncthreads();
    if (s_skip) return;

    // input fragments (B-operand: col = m-row), two 16-row groups
    u32x4 a[2][10];
    #pragma unroll
    for (int ms = 0; ms < 2; ++ms){
        const float* rp = S + (base + 32 * w + 16 * ms + lr) * D_;
        #pragma unroll
        for (int ks = 0; ks < 10; ++ks){
            const int k0 = ks * 32 + lg * 8;
            f32x4 v0 = {0,0,0,0}, v1 = {0,0,0,0};
            if (k0 + 4 <= D_) v0 = *(const f32x4*)(rp + k0);
            if (k0 + 8 <= D_) v1 = *(const f32x4*)(rp + k0 + 4);
            u32x4 u;
            u[0] = pk_bf16(v0[0], v0[1]);
            u[1] = pk_bf16(v0[2], v0[3]);
            u[2] = pk_bf16(v1[0], v1[1]);
            u[3] = pk_bf16(v1[2], v1[3]);
            a[ms][ks] = u;
        }
    }

    // Wb slice staging: slice = 32 e-rows x 320 = 1280 16B-chunks, 5/thread
    const unsigned short* srcW[5];
    int offW[5];                                 // u16 offset within one buffer
    #pragma unroll
    for (int j = 0; j < 5; ++j){
        const int id = tid + 256 * j;            // 0..1279
        const int row = id / 40, c = id % 40;
        srcW[j] = Wb + row * DP + c * 8;
        offW[j] = row * 320 + (c ^ (row & 7)) * 8;
    }
    unsigned short* const WlBase = &Wl[0][0][0];

    // prologue: stage slice 0 into buf 0
    u32x4 pW[5];
    #pragma unroll
    for (int j = 0; j < 5; ++j) pW[j] = *(const u32x4*)srcW[j];
    #pragma unroll
    for (int j = 0; j < 5; ++j) *(u32x4*)(WlBase + offW[j]) = pW[j];
    __syncthreads();

    int cur = 0;
    #pragma unroll 1
    for (int sl = 0; sl < 10; ++sl){
        const bool notlast = (sl < 9);
        if (notlast){
            #pragma unroll
            for (int j = 0; j < 5; ++j){ srcW[j] += 32 * DP; pW[j] = *(const u32x4*)srcW[j]; }
        }

        const unsigned short* Wc = WlBase + cur * 10240;
        #pragma unroll
        for (int es2 = 0; es2 < 2; ++es2){
            const int es = 2 * sl + es2;
            f32x4 acc0 = {0,0,0,0}, acc1 = {0,0,0,0};
            const unsigned short* wrow = Wc + (es2 * 16 + lr) * 320;
            #pragma unroll
            for (int ks = 0; ks < 10; ++ks){
                const int cc = (((ks << 2) | lg) ^ sw3) << 3;
                bf16x8 bf = ld_bf8(wrow + cc);                  // A: row=e, k=d
                acc0 = mfma16(bf, __builtin_bit_cast(bf16x8, a[0][ks]), acc0);
                acc1 = mfma16(bf, __builtin_bit_cast(bf16x8, a[1][ks]), acc1);
            }
            // lane holds D[e = es*16 + 4*lg + r][m = lr]
            const int e0 = es * 16 + lg * 4;
            f32x4 bv = {0,0,0,0};
            if (e0 + 4 <= D_) bv = *(const f32x4*)(bias + e0);
            else {
                #pragma unroll
                for (int r = 0; r < 4; ++r) bv[r] = (e0 + r < D_) ? bias[e0 + r] : 0.f;
            }
            float s0[4], s1[4];
            #pragma unroll
            for (int r = 0; r < 4; ++r){
                float t0v = acc0[r] + bv[r]; s0[r] = t0v > 0.f ? t0v : 0.f;
                float t1v = acc1[r] + bv[r]; s1[r] = t1v > 0.f ? t1v : 0.f;
            }
            const u32x2 o0 = { pk_bf16(s0[0], s0[1]), pk_bf16(s0[2], s0[3]) };
            const u32x2 o1 = { pk_bf16(s1[0], s1[1]), pk_bf16(s1[2], s1[3]) };
            *(u32x2*)(Dst + (base + 32 * w + lr) * DP + e0)      = o0;
            *(u32x2*)(Dst + (base + 32 * w + 16 + lr) * DP + e0) = o1;
        }

        if (notlast){
            // write next slice to the OTHER buffer (no reader yet -> no hazard)
            unsigned short* Wn = WlBase + (cur ^ 1) * 10240;
            #pragma unroll
            for (int j = 0; j < 5; ++j) *(u32x4*)(Wn + offW[j]) = pW[j];
        }
        __syncthreads();
        cur ^= 1;
    }
}

// ---------------- K3: flash attention (FROZEN from r12: 303us/166us config) --
// mask is int32: 0 = keep, nonzero = masked out
__global__ __launch_bounds__(256, 2) void k_attn(const int* __restrict__ mask,
        const unsigned short* __restrict__ Px, const unsigned short* __restrict__ Py,
        const unsigned short* __restrict__ yT, float* __restrict__ out){
    __shared__ unsigned short Yp_lds[KV][320];   // linear; XOR-swizzled write/read
    __shared__ unsigned short yT_lds[DV][32];    // linear; XOR-swizzled write/read
    __shared__ unsigned short P_lds[BM][40];     // padded (ds-written)

    const int tid = threadIdx.x;
    const int w = tid >> 6, l = tid & 63;
    const int lr = l & 15, lg = l >> 4;
    const int sw3 = lr & 7;          // Yp read swizzle: chunk ^= sw3
    const int s2  = (lr >> 1) & 3;   // yT read swizzle: chunk ^= s2

    // XCD-bijective swizzle: all 16 s-blocks of a batch land on one XCD
    const int bid = blockIdx.x;              // 1024
    const int xcd = bid & 7;
    const int g = bid >> 3;
    const int b = xcd + 8 * (g >> 4);
    const int s0 = (g & 15) * BM;

    // Q fragments: wave w owns rows s0+16w .. s0+16w+15 (B-operand: col = lr)
    u32x4 q[10];
    {
        const unsigned short* qp = Px + ((long)b * LX_ + s0 + 16 * w + lr) * DP + lg * 8;
        #pragma unroll
        for (int ks = 0; ks < 10; ++ks) q[ks] = *(const u32x4*)(qp + ks * 32);
    }

    // ---- staging address setup (loop-invariant; dst chunk XOR-swizzled) ----
    const unsigned short* srcYp[5];
    unsigned short*       dstYp[5];
    #pragma unroll
    for (int j = 0; j < 5; ++j){
        const int id = tid + 256 * j;            // 0..1279
        const int row = id / 40, c = id % 40;
        srcYp[j] = Py + ((long)b * LY_ + row) * DP + c * 8;
        dstYp[j] = &Yp_lds[row][(c ^ (row & 7)) * 8];
    }
    const unsigned short* srcYT[5];
    unsigned short*       dstYT[5];
    #pragma unroll
    for (int j = 0; j < 5; ++j){
        const int id = tid + 256 * j;            // valid if < 1216
        const int row = (id >> 2) < DV ? (id >> 2) : (DV - 1);
        const int c = id & 3;
        srcYT[j] = yT + ((long)b * DV + row) * LY_ + c * 8;
        dstYT[j] = &yT_lds[row][(c ^ ((row >> 1) & 3)) * 8];
    }
    const bool v4 = (tid < 192);                 // j=4 validity for yT chunks

    const int* mrow = mask + (long)b * LY_;

    // ---- prologue: stage tile 0 ----
    u32x4 pA[5], pT[5];
    #pragma unroll
    for (int j = 0; j < 5; ++j) pA[j] = *(const u32x4*)srcYp[j];
    #pragma unroll
    for (int j = 0; j < 4; ++j) pT[j] = *(const u32x4*)srcYT[j];
    if (v4) pT[4] = *(const u32x4*)srcYT[4];
    int4 m0v = *(const int4*)(mrow + lg * 4);
    int4 m1v = *(const int4*)(mrow + 16 + lg * 4);
    #pragma unroll
    for (int j = 0; j < 5; ++j) *(u32x4*)dstYp[j] = pA[j];
    #pragma unroll
    for (int j = 0; j < 4; ++j) *(u32x4*)dstYT[j] = pT[j];
    if (v4) *(u32x4*)dstYT[4] = pT[4];
    __syncthreads();

    f32x4 acc[19];
    #pragma unroll
    for (int n = 0; n < 19; ++n) acc[n] = f32x4{0,0,0,0};
    float m_r = -INFINITY;    // running max for s-row = s0+16w+lr
    float l_r = 0.f;

    for (int it = 0; it < NT; ++it){
        const bool notlast = (it < NT - 1);

        // ---- A: issue next tile's global loads (consumed after barrier) ----
        int4 mn0, mn1;
        if (notlast){
            #pragma unroll
            for (int j = 0; j < 5; ++j){ srcYp[j] += KV * DP; pA[j] = *(const u32x4*)srcYp[j]; }
            #pragma unroll
            for (int j = 0; j < 4; ++j){ srcYT[j] += KV;      pT[j] = *(const u32x4*)srcYT[j]; }
            srcYT[4] += KV;
            if (v4) pT[4] = *(const u32x4*)srcYT[4];
            mn0 = *(const int4*)(mrow + (it + 1) * KV + lg * 4);
            mn1 = *(const int4*)(mrow + (it + 1) * KV + 16 + lg * 4);
        }

        // ---- B: compute on current tile (skip if fully masked) ----
        const int allm = (m0v.x && m0v.y && m0v.z && m0v.w &&
                          m1v.x && m1v.y && m1v.z && m1v.w) ? 1 : 0;
        if (!__all(allm)){
            // S^T = Yp @ Q^T : lane holds S[t = it*KV+16*sub+4*lg+r][s = s0+16w+lr]
            f32x4 sv0 = {0,0,0,0}, sv1 = {0,0,0,0};
            #pragma unroll
            for (int ks = 0; ks < 10; ++ks){
                const int cc = (((ks << 2) | lg) ^ sw3) << 3;   // swizzled u16 col
                bf16x8 qf = __builtin_bit_cast(bf16x8, q[ks]);
                bf16x8 a0 = ld_bf8(&Yp_lds[lr][cc]);
                bf16x8 a1 = ld_bf8(&Yp_lds[16 + lr][cc]);
                sv0 = mfma16(a0, qf, sv0);
                sv1 = mfma16(a1, qf, sv1);
            }

            float v0[4], v1[4];
            v0[0] = sv0[0] + (m0v.x ? -3.0e38f : 0.f);
            v0[1] = sv0[1] + (m0v.y ? -3.0e38f : 0.f);
            v0[2] = sv0[2] + (m0v.z ? -3.0e38f : 0.f);
            v0[3] = sv0[3] + (m0v.w ? -3.0e38f : 0.f);
            v1[0] = sv1[0] + (m1v.x ? -3.0e38f : 0.f);
            v1[1] = sv1[1] + (m1v.y ? -3.0e38f : 0.f);
            v1[2] = sv1[2] + (m1v.z ? -3.0e38f : 0.f);
            v1[3] = sv1[3] + (m1v.w ? -3.0e38f : 0.f);

            float mx = fmaxf(fmaxf(fmaxf(v0[0], v0[1]), fmaxf(v0[2], v0[3])),
                             fmaxf(fmaxf(v1[0], v1[1]), fmaxf(v1[2], v1[3])));
            mx = fmaxf(mx, __shfl_xor(mx, 16));
            mx = fmaxf(mx, __shfl_xor(mx, 32));
            const float nm = fmaxf(m_r, mx);

            float p0[4], p1[4];
            float ps = 0.f;
            #pragma unroll
            for (int r = 0; r < 4; ++r){
                p0[r] = __expf(v0[r] - nm);
                p1[r] = __expf(v1[r] - nm);
                ps += p0[r] + p1[r];
            }
            ps += __shfl_xor(ps, 16);
            ps += __shfl_xor(ps, 32);
            const float sc = __expf(m_r - nm);   // first tile: exp(-inf)=0
            l_r = l_r * sc + ps;
            m_r = nm;

            // rescale acc rows (s = 4*lg + r): broadcast sc from lane 4*lg+r
            float scr[4];
            #pragma unroll
            for (int r = 0; r < 4; ++r) scr[r] = __shfl(sc, lg * 4 + r);
            #pragma unroll
            for (int n = 0; n < 19; ++n){
                #pragma unroll
                for (int r = 0; r < 4; ++r) acc[n][r] *= scr[r];
            }

            // pack P -> bf16, write own wave's rows (within-wave dependency only)
            const unsigned c00 = pk_bf16(p0[0], p0[1]);
            const unsigned c01 = pk_bf16(p0[2], p0[3]);
            const unsigned c10 = pk_bf16(p1[0], p1[1]);
            const unsigned c11 = pk_bf16(p1[2], p1[3]);
            *(u32x2*)&P_lds[16 * w + lr][4 * lg]      = u32x2{c00, c01};
            *(u32x2*)&P_lds[16 * w + lr][16 + 4 * lg] = u32x2{c10, c11};

            // O += P @ y (yT read with swizzled chunk)
            bf16x8 pf = ld_bf8(&P_lds[16 * w + lr][lg * 8]);
            const int vcc = (lg ^ s2) << 3;
            #pragma unroll
            for (int n = 0; n < 19; ++n){
                bf16x8 vf = ld_bf8(&yT_lds[n * 16 + lr][vcc]);
                acc[n] = mfma16(pf, vf, acc[n]);
            }
        }

        __syncthreads();           // all waves done reading LDS
        if (notlast){
            #pragma unroll
            for (int j = 0; j < 5; ++j) *(u32x4*)dstYp[j] = pA[j];
            #pragma unroll
            for (int j = 0; j < 4; ++j) *(u32x4*)dstYT[j] = pT[j];
            if (v4) *(u32x4*)dstYT[4] = pT[4];
            m0v = mn0; m1v = mn1;
        }
        __syncthreads();           // LDS ready for next iteration
    }

    // normalize: 1/l for rows s = 4*lg + r via broadcast
    const float il = 1.f / l_r;
    float invr[4];
    #pragma unroll
    for (int r = 0; r < 4; ++r) invr[r] = __shfl(il, lg * 4 + r);

    #pragma unroll
    for (int n = 0; n < 19; ++n){
        const int d = n * 16 + lr;
        if (d < D_){
            #pragma unroll
            for (int r = 0; r < 4; ++r){
                out[((long)b * LX_ + s0 + 16 * w + lg * 4 + r) * D_ + d] = acc[n][r] * invr[r];
            }
        }
    }
}

extern "C" void kernel_launch(void* const* d_in, const int* in_sizes, int n_in,
                              void* d_out, int out_size, void* d_ws, size_t ws_size,
                              hipStream_t stream){
    const float* x = (const float*)d_in[0];
    const float* y = (const float*)d_in[1];
    const int* ymask = (const int*)d_in[2];
    const float* W = (const float*)d_in[3];
    const float* bias = (const float*)d_in[4];
    float* out = (float*)d_out;

    unsigned short* Wb  = (unsigned short*)d_ws;
    unsigned short* Px  = (unsigned short*)((char*)d_ws + (1 << 18));
    unsigned short* Py  = (unsigned short*)((char*)d_ws + (1 << 18) + 41943040LL);
    unsigned short* yTw = (unsigned short*)((char*)d_ws + (1 << 18) + 83886080LL);

    // k_pre: 5120 ytrans blocks + 400 wconv blocks (independent outputs)
    hipLaunchKernelGGL(k_pre,  dim3(5520), dim3(256), 0, stream, y, ymask, W, yTw, Wb);
    hipLaunchKernelGGL(k_proj, dim3(1024), dim3(256), 0, stream, x, y, bias, ymask, Wb, Px, Py);
    hipLaunchKernelGGL(k_attn, dim3(1024), dim3(256), 0, stream, ymask, Px, Py, yTw, out);
}

// Round 16
// 245.801 us; speedup vs baseline: 1.5922x; 1.0119x over previous
//
#include <hip/hip_runtime.h>
#include <cmath>

#define B_   64
#define LX_  1024
#define LY_  1024
#define D_   300
#define DP   320      // padded K / e dimension
#define DV   304      // padded d for PV (19 * 16)
#define BM   64       // s-tile rows per block (flash attn)
#define KV   32       // t-tile
#define NT   (LY_ / KV)

using f32x4  = __attribute__((ext_vector_type(4))) float;
using bf16x8 = __attribute__((ext_vector_type(8))) __bf16;
using u32x4  = __attribute__((ext_vector_type(4))) unsigned int;
using u32x2  = __attribute__((ext_vector_type(2))) unsigned int;

static __device__ __forceinline__ unsigned short f2b(float f){
    unsigned u = __builtin_bit_cast(unsigned, f);
    u += 0x7FFFu + ((u >> 16) & 1u);          // round-to-nearest-even
    return (unsigned short)(u >> 16);
}

static __device__ __forceinline__ unsigned pk_bf16(float lo, float hi){
    unsigned r;
    asm volatile("v_cvt_pk_bf16_f32 %0, %1, %2" : "=v"(r) : "v"(lo), "v"(hi));
    return r;
}

static __device__ __forceinline__ bf16x8 ld_bf8(const unsigned short* p){
    u32x4 u = *(const u32x4*)p;
    return __builtin_bit_cast(bf16x8, u);
}

static __device__ __forceinline__ f32x4 mfma16(bf16x8 a, bf16x8 b, f32x4 c){
    return __builtin_amdgcn_mfma_f32_16x16x32_bf16(a, b, c, 0, 0, 0);
}

// ---------------- K0+K2 fused: wconv (blocks >= 5120) + ytrans (blocks < 5120)
__global__ __launch_bounds__(256) void k_pre(const float* __restrict__ Y,
        const int* __restrict__ mask, const float* __restrict__ W,
        unsigned short* __restrict__ yT, unsigned short* __restrict__ Wb){
    const int bid = blockIdx.x;
    const int tid = threadIdx.x;

    if (bid >= 5120){                      // ---- wconv part (400 blocks) ----
        const int i = (bid - 5120) * 256 + tid;
        if (i < DP * DP){
            const int e = i / DP, d = i % DP;
            float v = (e < D_ && d < D_) ? W[e * D_ + d] : 0.f;
            Wb[i] = f2b(v);
        }
        return;
    }

    // ---- ytrans part (5120 blocks): y (b,t,d f32) -> yT (b,d,t bf16) ----
    __shared__ float tile[64][65];
    const int b  = bid / 80;
    const int tt = (bid % 80) / 5;
    const int dt = bid % 5;
    const int t0 = tt * 64, d0 = dt * 64;
    const int dl = tid & 63, qq = tid >> 6;

    // block-uniform skip: all 64 t-rows masked -> yT never consumed
    const int mv = mask[b * LY_ + t0 + dl];
    if (__all(mv != 0)) return;

    #pragma unroll
    for (int r = 0; r < 16; ++r){
        const int tl = qq * 16 + r;
        const int d = d0 + dl;
        float v = (d < D_) ? Y[((long)b * LY_ + t0 + tl) * D_ + d] : 0.f;
        tile[tl][dl] = v;
    }
    __syncthreads();
    #pragma unroll
    for (int r = 0; r < 16; ++r){
        const int drow = d0 + qq * 16 + r;
        if (drow < DV){
            float v = (drow < D_) ? tile[dl][qq * 16 + r] : 0.f;
            yT[((long)b * DV + drow) * LY_ + t0 + dl] = f2b(v);
        }
    }
}

// ---------------- K1: proj = relu(Z @ W^T + b) -------------------------------
// Dual-chain MFMA + Wb slices staged through LDS (broadcast reads, r15 win).
__global__ __launch_bounds__(256) void k_proj(const float* __restrict__ X,
        const float* __restrict__ Y, const float* __restrict__ bias,
        const int* __restrict__ mask, const unsigned short* __restrict__ Wb,
        unsigned short* __restrict__ Px, unsigned short* __restrict__ Py){
    __shared__ unsigned short Wl[2][32][320];    // 2 x 20KB, XOR-swizzled chunks
    __shared__ int s_skip;

    const int tid = threadIdx.x;
    const int w = tid >> 6, l = tid & 63;
    const int lr = l & 15, lg = l >> 4;
    const int sw3 = lr & 7;
    const long m0 = (long)blockIdx.x * 128;
    const bool isX = (m0 < (long)B_ * LX_);
    const float* S = isX ? X : Y;
    unsigned short* Dst = isX ? Px : Py;
    const long base = isX ? m0 : m0 - (long)B_ * LX_;

    // block-uniform masked skip (barrier-safe: decided before any staging)
    int unmask = 1;
    if (!isX){
        const int bb = (int)(base >> 10);
        const int trow = ((int)base & 1023) + (tid & 127);
        unmask = (mask[bb * LY_ + trow] == 0) ? 1 : 0;
    }
    if (tid == 0) s_skip = 1;
    __syncthreads();
    if (unmask) s_skip = 0;
    __syncthreads();
    if (s_skip) return;

    // input fragments (B-operand: col = m-row), two 16-row groups
    u32x4 a[2][10];
    #pragma unroll
    for (int ms = 0; ms < 2; ++ms){
        const float* rp = S + (base + 32 * w + 16 * ms + lr) * D_;
        #pragma unroll
        for (int ks = 0; ks < 10; ++ks){
            const int k0 = ks * 32 + lg * 8;
            f32x4 v0 = {0,0,0,0}, v1 = {0,0,0,0};
            if (k0 + 4 <= D_) v0 = *(const f32x4*)(rp + k0);
            if (k0 + 8 <= D_) v1 = *(const f32x4*)(rp + k0 + 4);
            u32x4 u;
            u[0] = pk_bf16(v0[0], v0[1]);
            u[1] = pk_bf16(v0[2], v0[3]);
            u[2] = pk_bf16(v1[0], v1[1]);
            u[3] = pk_bf16(v1[2], v1[3]);
            a[ms][ks] = u;
        }
    }

    // Wb slice staging: slice = 32 e-rows x 320 = 1280 16B-chunks, 5/thread
    const unsigned short* srcW[5];
    int offW[5];                                 // u16 offset within one buffer
    #pragma unroll
    for (int j = 0; j < 5; ++j){
        const int id = tid + 256 * j;            // 0..1279
        const int row = id / 40, c = id % 40;
        srcW[j] = Wb + row * DP + c * 8;
        offW[j] = row * 320 + (c ^ (row & 7)) * 8;
    }
    unsigned short* const WlBase = &Wl[0][0][0];

    // prologue: stage slice 0 into buf 0
    u32x4 pW[5];
    #pragma unroll
    for (int j = 0; j < 5; ++j) pW[j] = *(const u32x4*)srcW[j];
    #pragma unroll
    for (int j = 0; j < 5; ++j) *(u32x4*)(WlBase + offW[j]) = pW[j];
    __syncthreads();

    int cur = 0;
    #pragma unroll 1
    for (int sl = 0; sl < 10; ++sl){
        const bool notlast = (sl < 9);
        if (notlast){
            #pragma unroll
            for (int j = 0; j < 5; ++j){ srcW[j] += 32 * DP; pW[j] = *(const u32x4*)srcW[j]; }
        }

        const unsigned short* Wc = WlBase + cur * 10240;
        #pragma unroll
        for (int es2 = 0; es2 < 2; ++es2){
            const int es = 2 * sl + es2;
            f32x4 acc0 = {0,0,0,0}, acc1 = {0,0,0,0};
            const unsigned short* wrow = Wc + (es2 * 16 + lr) * 320;
            #pragma unroll
            for (int ks = 0; ks < 10; ++ks){
                const int cc = (((ks << 2) | lg) ^ sw3) << 3;
                bf16x8 bf = ld_bf8(wrow + cc);                  // A: row=e, k=d
                acc0 = mfma16(bf, __builtin_bit_cast(bf16x8, a[0][ks]), acc0);
                acc1 = mfma16(bf, __builtin_bit_cast(bf16x8, a[1][ks]), acc1);
            }
            // lane holds D[e = es*16 + 4*lg + r][m = lr]
            const int e0 = es * 16 + lg * 4;
            f32x4 bv = {0,0,0,0};
            if (e0 + 4 <= D_) bv = *(const f32x4*)(bias + e0);
            else {
                #pragma unroll
                for (int r = 0; r < 4; ++r) bv[r] = (e0 + r < D_) ? bias[e0 + r] : 0.f;
            }
            float s0[4], s1[4];
            #pragma unroll
            for (int r = 0; r < 4; ++r){
                float t0v = acc0[r] + bv[r]; s0[r] = t0v > 0.f ? t0v : 0.f;
                float t1v = acc1[r] + bv[r]; s1[r] = t1v > 0.f ? t1v : 0.f;
            }
            const u32x2 o0 = { pk_bf16(s0[0], s0[1]), pk_bf16(s0[2], s0[3]) };
            const u32x2 o1 = { pk_bf16(s1[0], s1[1]), pk_bf16(s1[2], s1[3]) };
            *(u32x2*)(Dst + (base + 32 * w + lr) * DP + e0)      = o0;
            *(u32x2*)(Dst + (base + 32 * w + 16 + lr) * DP + e0) = o1;
        }

        if (notlast){
            unsigned short* Wn = WlBase + (cur ^ 1) * 10240;
            #pragma unroll
            for (int j = 0; j < 5; ++j) *(u32x4*)(Wn + offW[j]) = pW[j];
        }
        __syncthreads();
        cur ^= 1;
    }
}

// ---------------- K3: flash attention (r12 + setprio + exact-skip rescale) --
// mask is int32: 0 = keep, nonzero = masked out
__global__ __launch_bounds__(256, 2) void k_attn(const int* __restrict__ mask,
        const unsigned short* __restrict__ Px, const unsigned short* __restrict__ Py,
        const unsigned short* __restrict__ yT, float* __restrict__ out){
    __shared__ unsigned short Yp_lds[KV][320];   // linear; XOR-swizzled write/read
    __shared__ unsigned short yT_lds[DV][32];    // linear; XOR-swizzled write/read
    __shared__ unsigned short P_lds[BM][40];     // padded (ds-written)

    const int tid = threadIdx.x;
    const int w = tid >> 6, l = tid & 63;
    const int lr = l & 15, lg = l >> 4;
    const int sw3 = lr & 7;          // Yp read swizzle: chunk ^= sw3
    const int s2  = (lr >> 1) & 3;   // yT read swizzle: chunk ^= s2

    // XCD-bijective swizzle: all 16 s-blocks of a batch land on one XCD
    const int bid = blockIdx.x;              // 1024
    const int xcd = bid & 7;
    const int g = bid >> 3;
    const int b = xcd + 8 * (g >> 4);
    const int s0 = (g & 15) * BM;

    // Q fragments: wave w owns rows s0+16w .. s0+16w+15 (B-operand: col = lr)
    u32x4 q[10];
    {
        const unsigned short* qp = Px + ((long)b * LX_ + s0 + 16 * w + lr) * DP + lg * 8;
        #pragma unroll
        for (int ks = 0; ks < 10; ++ks) q[ks] = *(const u32x4*)(qp + ks * 32);
    }

    // ---- staging address setup (loop-invariant; dst chunk XOR-swizzled) ----
    const unsigned short* srcYp[5];
    unsigned short*       dstYp[5];
    #pragma unroll
    for (int j = 0; j < 5; ++j){
        const int id = tid + 256 * j;            // 0..1279
        const int row = id / 40, c = id % 40;
        srcYp[j] = Py + ((long)b * LY_ + row) * DP + c * 8;
        dstYp[j] = &Yp_lds[row][(c ^ (row & 7)) * 8];
    }
    const unsigned short* srcYT[5];
    unsigned short*       dstYT[5];
    #pragma unroll
    for (int j = 0; j < 5; ++j){
        const int id = tid + 256 * j;            // valid if < 1216
        const int row = (id >> 2) < DV ? (id >> 2) : (DV - 1);
        const int c = id & 3;
        srcYT[j] = yT + ((long)b * DV + row) * LY_ + c * 8;
        dstYT[j] = &yT_lds[row][(c ^ ((row >> 1) & 3)) * 8];
    }
    const bool v4 = (tid < 192);                 // j=4 validity for yT chunks

    const int* mrow = mask + (long)b * LY_;

    // ---- prologue: stage tile 0 ----
    u32x4 pA[5], pT[5];
    #pragma unroll
    for (int j = 0; j < 5; ++j) pA[j] = *(const u32x4*)srcYp[j];
    #pragma unroll
    for (int j = 0; j < 4; ++j) pT[j] = *(const u32x4*)srcYT[j];
    if (v4) pT[4] = *(const u32x4*)srcYT[4];
    int4 m0v = *(const int4*)(mrow + lg * 4);
    int4 m1v = *(const int4*)(mrow + 16 + lg * 4);
    #pragma unroll
    for (int j = 0; j < 5; ++j) *(u32x4*)dstYp[j] = pA[j];
    #pragma unroll
    for (int j = 0; j < 4; ++j) *(u32x4*)dstYT[j] = pT[j];
    if (v4) *(u32x4*)dstYT[4] = pT[4];
    __syncthreads();

    f32x4 acc[19];
    #pragma unroll
    for (int n = 0; n < 19; ++n) acc[n] = f32x4{0,0,0,0};
    float m_r = -INFINITY;    // running max for s-row = s0+16w+lr
    float l_r = 0.f;

    for (int it = 0; it < NT; ++it){
        const bool notlast = (it < NT - 1);

        // ---- A: issue next tile's global loads (consumed after barrier) ----
        int4 mn0, mn1;
        if (notlast){
            #pragma unroll
            for (int j = 0; j < 5; ++j){ srcYp[j] += KV * DP; pA[j] = *(const u32x4*)srcYp[j]; }
            #pragma unroll
            for (int j = 0; j < 4; ++j){ srcYT[j] += KV;      pT[j] = *(const u32x4*)srcYT[j]; }
            srcYT[4] += KV;
            if (v4) pT[4] = *(const u32x4*)srcYT[4];
            mn0 = *(const int4*)(mrow + (it + 1) * KV + lg * 4);
            mn1 = *(const int4*)(mrow + (it + 1) * KV + 16 + lg * 4);
        }

        // ---- B: compute on current tile (skip if fully masked) ----
        const int allm = (m0v.x && m0v.y && m0v.z && m0v.w &&
                          m1v.x && m1v.y && m1v.z && m1v.w) ? 1 : 0;
        if (!__all(allm)){
            // S^T = Yp @ Q^T : lane holds S[t = it*KV+16*sub+4*lg+r][s = s0+16w+lr]
            f32x4 sv0 = {0,0,0,0}, sv1 = {0,0,0,0};
            __builtin_amdgcn_s_setprio(1);
            #pragma unroll
            for (int ks = 0; ks < 10; ++ks){
                const int cc = (((ks << 2) | lg) ^ sw3) << 3;   // swizzled u16 col
                bf16x8 qf = __builtin_bit_cast(bf16x8, q[ks]);
                bf16x8 a0 = ld_bf8(&Yp_lds[lr][cc]);
                bf16x8 a1 = ld_bf8(&Yp_lds[16 + lr][cc]);
                sv0 = mfma16(a0, qf, sv0);
                sv1 = mfma16(a1, qf, sv1);
            }
            __builtin_amdgcn_s_setprio(0);

            float v0[4], v1[4];
            v0[0] = sv0[0] + (m0v.x ? -3.0e38f : 0.f);
            v0[1] = sv0[1] + (m0v.y ? -3.0e38f : 0.f);
            v0[2] = sv0[2] + (m0v.z ? -3.0e38f : 0.f);
            v0[3] = sv0[3] + (m0v.w ? -3.0e38f : 0.f);
            v1[0] = sv1[0] + (m1v.x ? -3.0e38f : 0.f);
            v1[1] = sv1[1] + (m1v.y ? -3.0e38f : 0.f);
            v1[2] = sv1[2] + (m1v.z ? -3.0e38f : 0.f);
            v1[3] = sv1[3] + (m1v.w ? -3.0e38f : 0.f);

            float mx = fmaxf(fmaxf(fmaxf(v0[0], v0[1]), fmaxf(v0[2], v0[3])),
                             fmaxf(fmaxf(v1[0], v1[1]), fmaxf(v1[2], v1[3])));
            mx = fmaxf(mx, __shfl_xor(mx, 16));
            mx = fmaxf(mx, __shfl_xor(mx, 32));
            const float nm = fmaxf(m_r, mx);

            float p0[4], p1[4];
            float ps = 0.f;
            #pragma unroll
            for (int r = 0; r < 4; ++r){
                p0[r] = __expf(v0[r] - nm);
                p1[r] = __expf(v1[r] - nm);
                ps += p0[r] + p1[r];
            }
            ps += __shfl_xor(ps, 16);
            ps += __shfl_xor(ps, 32);
            const float sc = __expf(m_r - nm);   // == 1.0f exactly when max didn't grow
            l_r = l_r * sc + ps;
            m_r = nm;

            // exact-skip rescale: rescale-by-1.0 is a no-op; skip it (no
            // numerical change -- absmax must stay bitwise-identical)
            if (!__all(sc == 1.0f)){
                float scr[4];
                #pragma unroll
                for (int r = 0; r < 4; ++r) scr[r] = __shfl(sc, lg * 4 + r);
                #pragma unroll
                for (int n = 0; n < 19; ++n){
                    #pragma unroll
                    for (int r = 0; r < 4; ++r) acc[n][r] *= scr[r];
                }
            }

            // pack P -> bf16, write own wave's rows (within-wave dependency only)
            const unsigned c00 = pk_bf16(p0[0], p0[1]);
            const unsigned c01 = pk_bf16(p0[2], p0[3]);
            const unsigned c10 = pk_bf16(p1[0], p1[1]);
            const unsigned c11 = pk_bf16(p1[2], p1[3]);
            *(u32x2*)&P_lds[16 * w + lr][4 * lg]      = u32x2{c00, c01};
            *(u32x2*)&P_lds[16 * w + lr][16 + 4 * lg] = u32x2{c10, c11};

            // O += P @ y (yT read with swizzled chunk)
            bf16x8 pf = ld_bf8(&P_lds[16 * w + lr][lg * 8]);
            const int vcc = (lg ^ s2) << 3;
            __builtin_amdgcn_s_setprio(1);
            #pragma unroll
            for (int n = 0; n < 19; ++n){
                bf16x8 vf = ld_bf8(&yT_lds[n * 16 + lr][vcc]);
                acc[n] = mfma16(pf, vf, acc[n]);
            }
            __builtin_amdgcn_s_setprio(0);
        }

        __syncthreads();           // all waves done reading LDS
        if (notlast){
            #pragma unroll
            for (int j = 0; j < 5; ++j) *(u32x4*)dstYp[j] = pA[j];
            #pragma unroll
            for (int j = 0; j < 4; ++j) *(u32x4*)dstYT[j] = pT[j];
            if (v4) *(u32x4*)dstYT[4] = pT[4];
            m0v = mn0; m1v = mn1;
        }
        __syncthreads();           // LDS ready for next iteration
    }

    // normalize: 1/l for rows s = 4*lg + r via broadcast
    const float il = 1.f / l_r;
    float invr[4];
    #pragma unroll
    for (int r = 0; r < 4; ++r) invr[r] = __shfl(il, lg * 4 + r);

    #pragma unroll
    for (int n = 0; n < 19; ++n){
        const int d = n * 16 + lr;
        if (d < D_){
            #pragma unroll
            for (int r = 0; r < 4; ++r){
                out[((long)b * LX_ + s0 + 16 * w + lg * 4 + r) * D_ + d] = acc[n][r] * invr[r];
            }
        }
    }
}

extern "C" void kernel_launch(void* const* d_in, const int* in_sizes, int n_in,
                              void* d_out, int out_size, void* d_ws, size_t ws_size,
                              hipStream_t stream){
    const float* x = (const float*)d_in[0];
    const float* y = (const float*)d_in[1];
    const int* ymask = (const int*)d_in[2];
    const float* W = (const float*)d_in[3];
    const float* bias = (const float*)d_in[4];
    float* out = (float*)d_out;

    unsigned short* Wb  = (unsigned short*)d_ws;
    unsigned short* Px  = (unsigned short*)((char*)d_ws + (1 << 18));
    unsigned short* Py  = (unsigned short*)((char*)d_ws + (1 << 18) + 41943040LL);
    unsigned short* yTw = (unsigned short*)((char*)d_ws + (1 << 18) + 83886080LL);

    // k_pre: 5120 ytrans blocks + 400 wconv blocks (independent outputs)
    hipLaunchKernelGGL(k_pre,  dim3(5520), dim3(256), 0, stream, y, ymask, W, yTw, Wb);
    hipLaunchKernelGGL(k_proj, dim3(1024), dim3(256), 0, stream, x, y, bias, ymask, Wb, Px, Py);
    hipLaunchKernelGGL(k_attn, dim3(1024), dim3(256), 0, stream, ymask, Px, Py, yTw, out);
}